// Round 1
// baseline (1057.986 us; speedup 1.0000x reference)
//
#include <hip/hip_runtime.h>

#define D 128

typedef __attribute__((ext_vector_type(8))) short bf16x8;
typedef __attribute__((ext_vector_type(4))) float f32x4;

__device__ inline unsigned short f2b(float f) {
    union { float f; unsigned int u; } v; v.f = f;
    unsigned int u = v.u;
    u += 0x7fffu + ((u >> 16) & 1u);
    return (unsigned short)(u >> 16);
}

// ---------- edge dtype probe: int64 storage => odd int32 words are all zero ----------
__global__ void detect_dtype(const int* __restrict__ ei, int E, int* __restrict__ flag) {
    if (blockIdx.x == 0 && threadIdx.x == 0) {
        int z = 0;
        int nprobe = (E > 32) ? 32 : E;
        for (int i = 0; i < nprobe; i++) z |= ei[2 * i + 1];
        flag[0] = (z == 0) ? 1 : 0;   // 1 = int64 storage, 0 = int32
    }
}

// ---------- CSR build ----------
__global__ void count_deg(const int* __restrict__ ei, int E, int n,
                          const int* __restrict__ flag, int* __restrict__ deg) {
    int i = blockIdx.x * blockDim.x + threadIdx.x;
    if (i >= E) return;
    int m = flag[0];
    int d = m ? ei[2 * (E + i)] : ei[E + i];
    if (d >= 0 && d < n) atomicAdd(&deg[d], 1);
}

__global__ void scan_deg(const int* __restrict__ deg, int* __restrict__ offsets, int n) {
    __shared__ int sums[1024];
    int tid = threadIdx.x;
    int chunk = (n + 1023) >> 10;
    int s = tid * chunk; if (s > n) s = n;
    int e = s + chunk;   if (e > n) e = n;
    int sum = 0;
    for (int i = s; i < e; i++) sum += deg[i];
    sums[tid] = sum;
    __syncthreads();
    for (int off = 1; off < 1024; off <<= 1) {
        int t = (tid >= off) ? sums[tid - off] : 0;
        __syncthreads();
        sums[tid] += t;
        __syncthreads();
    }
    int run = sums[tid] - sum;   // exclusive prefix
    for (int i = s; i < e; i++) { run += deg[i]; offsets[i + 1] = run; }
    if (tid == 0) offsets[0] = 0;
}

__global__ void fill_csr(const int* __restrict__ ei, int E, int n,
                         const int* __restrict__ flag, const int* __restrict__ offsets,
                         int* __restrict__ cursor, int* __restrict__ csr) {
    int i = blockIdx.x * blockDim.x + threadIdx.x;
    if (i >= E) return;
    int m = flag[0];
    int s = m ? ei[2 * i] : ei[i];
    int d = m ? ei[2 * (E + i)] : ei[E + i];
    if (d < 0 || d >= n) return;
    int pos = offsets[d] + atomicAdd(&cursor[d], 1);
    csr[pos] = s;
}

// ---------- weight transpose + bf16 convert: Wt[l][which][c][k] = W[l][k][c] ----------
__global__ void conv_w(const float* __restrict__ W1, const float* __restrict__ W2,
                       unsigned short* __restrict__ Wt, int L) {
    int i = blockIdx.x * blockDim.x + threadIdx.x;
    int total = L * 2 * D * D;
    if (i >= total) return;
    int l = i / (2 * D * D);
    int rem = i - l * 2 * D * D;
    int which = rem / (D * D);
    int idx = rem - which * D * D;
    int c = idx >> 7, k = idx & 127;
    const float* W = which ? W2 : W1;
    Wt[i] = f2b(W[(size_t)l * D * D + k * D + c]);
}

// ---------- aggregation: A_bf16[node] = bf16( x[node] + sum_{src in N(node)} x[src] ) ----------
__global__ void agg_kernel(const float* __restrict__ x, const int* __restrict__ csr,
                           const int* __restrict__ offsets, unsigned short* __restrict__ A,
                           int n) {
    int node = blockIdx.x * (blockDim.x >> 6) + (threadIdx.x >> 6);
    if (node >= n) return;
    int d2 = threadIdx.x & 63;   // float2 slot
    const float2* xr = (const float2*)(x + (size_t)node * D);
    float2 acc = xr[d2];
    int beg = offsets[node], end = offsets[node + 1];
    for (int i = beg; i < end; i++) {
        int s = csr[i];
        float2 v = ((const float2*)(x + (size_t)s * D))[d2];
        acc.x += v.x; acc.y += v.y;
    }
    unsigned int pk = (unsigned int)f2b(acc.x) | ((unsigned int)f2b(acc.y) << 16);
    ((unsigned int*)(A + (size_t)node * D))[d2] = pk;
}

// ---------- GEMM: out = relu(Ain @ W + bias); Ain [n][128] bf16, Wt [c][k] bf16 ----------
__global__ __launch_bounds__(256) void gemm_bf16(
    const unsigned short* __restrict__ Ain,
    const unsigned short* __restrict__ Wt,
    const float* __restrict__ bias,
    int n, int storeF32,
    unsigned short* __restrict__ outB, float* __restrict__ outF) {

    int wave = threadIdx.x >> 6;
    int lane = threadIdx.x & 63;
    int l16 = lane & 15, g = lane >> 4;
    int rowbase = blockIdx.x * 128 + wave * 32;

    f32x4 acc[2][8];
    for (int rf = 0; rf < 2; rf++)
        for (int cf = 0; cf < 8; cf++)
            acc[rf][cf] = (f32x4){0.f, 0.f, 0.f, 0.f};

    for (int ks = 0; ks < 4; ks++) {
        int k0 = ks * 32 + g * 8;
        bf16x8 a[2];
        #pragma unroll
        for (int rf = 0; rf < 2; rf++) {
            int row = rowbase + rf * 16 + l16;
            if (row >= n) row = n - 1;
            a[rf] = *((const bf16x8*)(Ain + (size_t)row * D + k0));
        }
        #pragma unroll
        for (int cf = 0; cf < 8; cf++) {
            int col = cf * 16 + l16;
            bf16x8 b = *((const bf16x8*)(Wt + col * D + k0));
            acc[0][cf] = __builtin_amdgcn_mfma_f32_16x16x32_bf16(a[0], b, acc[0][cf], 0, 0, 0);
            acc[1][cf] = __builtin_amdgcn_mfma_f32_16x16x32_bf16(a[1], b, acc[1][cf], 0, 0, 0);
        }
    }

    #pragma unroll
    for (int cf = 0; cf < 8; cf++) {
        int col = cf * 16 + l16;
        float bv = bias[col];
        #pragma unroll
        for (int rf = 0; rf < 2; rf++) {
            #pragma unroll
            for (int r = 0; r < 4; r++) {
                int row = rowbase + rf * 16 + g * 4 + r;
                if (row < n) {
                    float v = acc[rf][cf][r] + bv;
                    v = (v < 0.f) ? 0.f : v;
                    if (storeF32) outF[(size_t)row * D + col] = v;
                    else          outB[(size_t)row * D + col] = f2b(v);
                }
            }
        }
    }
}

extern "C" void kernel_launch(void* const* d_in, const int* in_sizes, int n_in,
                              void* d_out, int out_size, void* d_ws, size_t ws_size,
                              hipStream_t stream) {
    const float* x  = (const float*)d_in[0];
    const int*   ei = (const int*)d_in[1];
    const float* W1 = (const float*)d_in[2];
    const float* b1 = (const float*)d_in[3];
    const float* W2 = (const float*)d_in[4];
    const float* b2 = (const float*)d_in[5];
    float* out = (float*)d_out;

    int N = in_sizes[0] / D;
    int E = in_sizes[1] / 2;
    int L = in_sizes[3] / D;

    auto alignup = [](size_t v) { return (v + 255) & ~(size_t)255; };
    char* p = (char*)d_ws;
    int* flag    = (int*)p;            p += 256;
    int* deg     = (int*)p;            p += alignup((size_t)N * 4);
    int* offs    = (int*)p;            p += alignup((size_t)(N + 1) * 4);
    int* cursor  = (int*)p;            p += alignup((size_t)N * 4);
    int* csr     = (int*)p;            p += alignup((size_t)E * 4);
    unsigned short* Wt = (unsigned short*)p; p += alignup((size_t)L * 2 * D * D * 2);
    unsigned short* A  = (unsigned short*)p; p += alignup((size_t)N * D * 2);
    unsigned short* H  = (unsigned short*)p;

    hipMemsetAsync(deg, 0, (size_t)N * 4, stream);
    hipMemsetAsync(cursor, 0, (size_t)N * 4, stream);

    detect_dtype<<<1, 64, 0, stream>>>(ei, E, flag);
    count_deg<<<(E + 255) / 256, 256, 0, stream>>>(ei, E, N, flag, deg);
    scan_deg<<<1, 1024, 0, stream>>>(deg, offs, N);
    fill_csr<<<(E + 255) / 256, 256, 0, stream>>>(ei, E, N, flag, offs, cursor, csr);
    conv_w<<<(L * 2 * D * D + 255) / 256, 256, 0, stream>>>(W1, W2, Wt, L);

    for (int l = 0; l < L; l++) {
        const float* xin = (l == 0) ? x : out + (size_t)(l - 1) * N * D;
        agg_kernel<<<(N + 3) / 4, 256, 0, stream>>>(xin, csr, offs, A, N);
        gemm_bf16<<<(N + 127) / 128, 256, 0, stream>>>(
            A, Wt + (size_t)l * 2 * D * D, b1 + (size_t)l * D, N, 0, H, nullptr);
        gemm_bf16<<<(N + 127) / 128, 256, 0, stream>>>(
            H, Wt + (size_t)l * 2 * D * D + D * D, b2 + (size_t)l * D, N, 1,
            nullptr, out + (size_t)l * N * D);
    }
}

// Round 2
// 817.949 us; speedup vs baseline: 1.2935x; 1.2935x over previous
//
#include <hip/hip_runtime.h>

#define D 128

typedef __attribute__((ext_vector_type(8))) short bf16x8;
typedef __attribute__((ext_vector_type(4))) float f32x4;

__device__ inline unsigned short f2b(float f) {
    union { float f; unsigned int u; } v; v.f = f;
    unsigned int u = v.u;
    u += 0x7fffu + ((u >> 16) & 1u);
    return (unsigned short)(u >> 16);
}
__device__ inline float bl(unsigned int u) { union { unsigned int u; float f; } c; c.u = u << 16; return c.f; }
__device__ inline float bh(unsigned int u) { union { unsigned int u; float f; } c; c.u = u & 0xffff0000u; return c.f; }

// ---------- edge dtype probe: int64 storage => odd int32 words are all zero ----------
__global__ void detect_dtype(const int* __restrict__ ei, int E, int* __restrict__ flag) {
    if (blockIdx.x == 0 && threadIdx.x == 0) {
        int z = 0;
        int nprobe = (E > 32) ? 32 : E;
        for (int i = 0; i < nprobe; i++) z |= ei[2 * i + 1];
        flag[0] = (z == 0) ? 1 : 0;
    }
}

// ---------- CSR build ----------
__global__ void count_deg(const int* __restrict__ ei, int E, int n,
                          const int* __restrict__ flag, int* __restrict__ deg) {
    int i = blockIdx.x * blockDim.x + threadIdx.x;
    if (i >= E) return;
    int m = flag[0];
    int d = m ? ei[2 * (E + i)] : ei[E + i];
    if (d >= 0 && d < n) atomicAdd(&deg[d], 1);
}

__global__ void scan_deg(const int* __restrict__ deg, int* __restrict__ offsets, int n) {
    __shared__ int sums[1024];
    int tid = threadIdx.x;
    int chunk = (n + 1023) >> 10;
    int s = tid * chunk; if (s > n) s = n;
    int e = s + chunk;   if (e > n) e = n;
    int sum = 0;
    for (int i = s; i < e; i++) sum += deg[i];
    sums[tid] = sum;
    __syncthreads();
    for (int off = 1; off < 1024; off <<= 1) {
        int t = (tid >= off) ? sums[tid - off] : 0;
        __syncthreads();
        sums[tid] += t;
        __syncthreads();
    }
    int run = sums[tid] - sum;
    for (int i = s; i < e; i++) { run += deg[i]; offsets[i + 1] = run; }
    if (tid == 0) offsets[0] = 0;
}

__global__ void fill_csr(const int* __restrict__ ei, int E, int n,
                         const int* __restrict__ flag, const int* __restrict__ offsets,
                         int* __restrict__ cursor, int* __restrict__ csr) {
    int i = blockIdx.x * blockDim.x + threadIdx.x;
    if (i >= E) return;
    int m = flag[0];
    int s = m ? ei[2 * i] : ei[i];
    int d = m ? ei[2 * (E + i)] : ei[E + i];
    if (d < 0 || d >= n) return;
    int pos = offsets[d] + atomicAdd(&cursor[d], 1);
    csr[pos] = s;
}

// ---------- weight transpose + bf16: Wt[l][which][c][k] = W[l][k][c] ----------
__global__ void conv_w(const float* __restrict__ W1, const float* __restrict__ W2,
                       unsigned short* __restrict__ Wt, int L) {
    int i = blockIdx.x * blockDim.x + threadIdx.x;
    int total = L * 2 * D * D;
    if (i >= total) return;
    int l = i / (2 * D * D);
    int rem = i - l * 2 * D * D;
    int which = rem / (D * D);
    int idx = rem - which * D * D;
    int c = idx >> 7, k = idx & 127;
    const float* W = which ? W2 : W1;
    Wt[i] = f2b(W[(size_t)l * D * D + k * D + c]);
}

// ---------- x (fp32) -> xb (bf16) ----------
__global__ void conv_x(const float* __restrict__ x, unsigned short* __restrict__ xb, int total4) {
    int i = blockIdx.x * blockDim.x + threadIdx.x;
    if (i >= total4) return;
    float4 v = ((const float4*)x)[i];
    uint2 o;
    o.x = (unsigned int)f2b(v.x) | ((unsigned int)f2b(v.y) << 16);
    o.y = (unsigned int)f2b(v.z) | ((unsigned int)f2b(v.w) << 16);
    ((uint2*)xb)[i] = o;
}

// ---------- aggregation, bf16 gather: A = bf16( xb[node] + sum xb[src] ) ----------
// one wave per node; half-wave per row (32 lanes x 8B = 256B); 2x unroll => 4 rows in flight
__global__ void agg_bf16(const unsigned short* __restrict__ xb, const int* __restrict__ csr,
                         const int* __restrict__ offs, unsigned short* __restrict__ A, int n) {
    int node = blockIdx.x * (blockDim.x >> 6) + (threadIdx.x >> 6);
    if (node >= n) return;
    int lane = threadIdx.x & 63;
    int half = lane >> 5, l32 = lane & 31;
    const uint2* xv = (const uint2*)xb;   // 32 uint2 per row

    float a0 = 0.f, a1 = 0.f, a2 = 0.f, a3 = 0.f;
    if (half == 0) {
        uint2 sv = xv[(size_t)node * 32 + l32];
        a0 += bl(sv.x); a1 += bh(sv.x); a2 += bl(sv.y); a3 += bh(sv.y);
    }
    int beg = offs[node], end = offs[node + 1];
    int i = beg + half;
    for (; i + 2 < end; i += 4) {
        int s0 = csr[i], s1 = csr[i + 2];
        uint2 v0 = xv[(size_t)s0 * 32 + l32];
        uint2 v1 = xv[(size_t)s1 * 32 + l32];
        a0 += bl(v0.x); a1 += bh(v0.x); a2 += bl(v0.y); a3 += bh(v0.y);
        a0 += bl(v1.x); a1 += bh(v1.x); a2 += bl(v1.y); a3 += bh(v1.y);
    }
    if (i < end) {
        int s0 = csr[i];
        uint2 v0 = xv[(size_t)s0 * 32 + l32];
        a0 += bl(v0.x); a1 += bh(v0.x); a2 += bl(v0.y); a3 += bh(v0.y);
    }
    a0 += __shfl_xor(a0, 32);
    a1 += __shfl_xor(a1, 32);
    a2 += __shfl_xor(a2, 32);
    a3 += __shfl_xor(a3, 32);
    if (half == 0) {
        uint2 o;
        o.x = (unsigned int)f2b(a0) | ((unsigned int)f2b(a1) << 16);
        o.y = (unsigned int)f2b(a2) | ((unsigned int)f2b(a3) << 16);
        ((uint2*)A)[(size_t)node * 32 + l32] = o;
    }
}

// ---------- aggregation, fp32 gather (fallback) ----------
__global__ void agg_f32(const float* __restrict__ x, const int* __restrict__ csr,
                        const int* __restrict__ offsets, unsigned short* __restrict__ A, int n) {
    int node = blockIdx.x * (blockDim.x >> 6) + (threadIdx.x >> 6);
    if (node >= n) return;
    int d2 = threadIdx.x & 63;
    const float2* xr = (const float2*)(x + (size_t)node * D);
    float2 acc = xr[d2];
    int beg = offsets[node], end = offsets[node + 1];
    for (int i = beg; i < end; i++) {
        int s = csr[i];
        float2 v = ((const float2*)(x + (size_t)s * D))[d2];
        acc.x += v.x; acc.y += v.y;
    }
    unsigned int pk = (unsigned int)f2b(acc.x) | ((unsigned int)f2b(acc.y) << 16);
    ((unsigned int*)(A + (size_t)node * D))[d2] = pk;
}

// ---------- GEMM: out = relu(Ain @ W + bias) ----------
__global__ __launch_bounds__(256) void gemm_bf16(
    const unsigned short* __restrict__ Ain,
    const unsigned short* __restrict__ Wt,
    const float* __restrict__ bias,
    int n, int storeF32,
    unsigned short* __restrict__ outB, float* __restrict__ outF,
    unsigned short* __restrict__ outXB) {

    int wave = threadIdx.x >> 6;
    int lane = threadIdx.x & 63;
    int l16 = lane & 15, g = lane >> 4;
    int rowbase = blockIdx.x * 128 + wave * 32;

    f32x4 acc[2][8];
    for (int rf = 0; rf < 2; rf++)
        for (int cf = 0; cf < 8; cf++)
            acc[rf][cf] = (f32x4){0.f, 0.f, 0.f, 0.f};

    for (int ks = 0; ks < 4; ks++) {
        int k0 = ks * 32 + g * 8;
        bf16x8 a[2];
        #pragma unroll
        for (int rf = 0; rf < 2; rf++) {
            int row = rowbase + rf * 16 + l16;
            if (row >= n) row = n - 1;
            a[rf] = *((const bf16x8*)(Ain + (size_t)row * D + k0));
        }
        #pragma unroll
        for (int cf = 0; cf < 8; cf++) {
            int col = cf * 16 + l16;
            bf16x8 b = *((const bf16x8*)(Wt + col * D + k0));
            acc[0][cf] = __builtin_amdgcn_mfma_f32_16x16x32_bf16(a[0], b, acc[0][cf], 0, 0, 0);
            acc[1][cf] = __builtin_amdgcn_mfma_f32_16x16x32_bf16(a[1], b, acc[1][cf], 0, 0, 0);
        }
    }

    #pragma unroll
    for (int cf = 0; cf < 8; cf++) {
        int col = cf * 16 + l16;
        float bv = bias[col];
        #pragma unroll
        for (int rf = 0; rf < 2; rf++) {
            #pragma unroll
            for (int r = 0; r < 4; r++) {
                int row = rowbase + rf * 16 + g * 4 + r;
                if (row < n) {
                    float v = acc[rf][cf][r] + bv;
                    v = (v < 0.f) ? 0.f : v;
                    if (storeF32) {
                        outF[(size_t)row * D + col] = v;
                        if (outXB) outXB[(size_t)row * D + col] = f2b(v);
                    } else {
                        outB[(size_t)row * D + col] = f2b(v);
                    }
                }
            }
        }
    }
}

extern "C" void kernel_launch(void* const* d_in, const int* in_sizes, int n_in,
                              void* d_out, int out_size, void* d_ws, size_t ws_size,
                              hipStream_t stream) {
    const float* x  = (const float*)d_in[0];
    const int*   ei = (const int*)d_in[1];
    const float* W1 = (const float*)d_in[2];
    const float* b1 = (const float*)d_in[3];
    const float* W2 = (const float*)d_in[4];
    const float* b2 = (const float*)d_in[5];
    float* out = (float*)d_out;

    int N = in_sizes[0] / D;
    int E = in_sizes[1] / 2;
    int L = in_sizes[3] / D;

    auto alignup = [](size_t v) { return (v + 255) & ~(size_t)255; };
    size_t sz_flag = 256;
    size_t sz_deg  = alignup((size_t)N * 4);
    size_t sz_offs = alignup((size_t)(N + 1) * 4);
    size_t sz_cur  = alignup((size_t)N * 4);
    size_t sz_csr  = alignup((size_t)E * 4);
    size_t sz_wt   = alignup((size_t)L * 2 * D * D * 2);
    size_t sz_mat  = alignup((size_t)N * D * 2);
    size_t base = sz_flag + sz_deg + sz_offs + sz_cur + sz_csr + sz_wt;
    bool useBf16 = (base + 3 * sz_mat) <= ws_size;

    char* p = (char*)d_ws;
    int* flag    = (int*)p;            p += sz_flag;
    int* deg     = (int*)p;            p += sz_deg;
    int* offs    = (int*)p;            p += sz_offs;
    int* cursor  = (int*)p;            p += sz_cur;
    int* csr     = (int*)p;            p += sz_csr;
    unsigned short* Wt = (unsigned short*)p; p += sz_wt;
    unsigned short* A  = (unsigned short*)p; p += sz_mat;
    unsigned short* H  = (unsigned short*)p; p += sz_mat;
    unsigned short* XB = (unsigned short*)p;

    hipMemsetAsync(deg, 0, (size_t)N * 4, stream);
    hipMemsetAsync(cursor, 0, (size_t)N * 4, stream);

    detect_dtype<<<1, 64, 0, stream>>>(ei, E, flag);
    count_deg<<<(E + 255) / 256, 256, 0, stream>>>(ei, E, N, flag, deg);
    scan_deg<<<1, 1024, 0, stream>>>(deg, offs, N);
    fill_csr<<<(E + 255) / 256, 256, 0, stream>>>(ei, E, N, flag, offs, cursor, csr);
    conv_w<<<(L * 2 * D * D + 255) / 256, 256, 0, stream>>>(W1, W2, Wt, L);
    if (useBf16)
        conv_x<<<(N * D / 4 + 255) / 256, 256, 0, stream>>>(x, XB, N * D / 4);

    for (int l = 0; l < L; l++) {
        if (useBf16) {
            agg_bf16<<<(N + 3) / 4, 256, 0, stream>>>(XB, csr, offs, A, N);
        } else {
            const float* xin = (l == 0) ? x : out + (size_t)(l - 1) * N * D;
            agg_f32<<<(N + 3) / 4, 256, 0, stream>>>(xin, csr, offs, A, N);
        }
        gemm_bf16<<<(N + 127) / 128, 256, 0, stream>>>(
            A, Wt + (size_t)l * 2 * D * D, b1 + (size_t)l * D, N, 0, H, nullptr, nullptr);
        unsigned short* nextXB = (useBf16 && l + 1 < L) ? XB : nullptr;
        gemm_bf16<<<(N + 127) / 128, 256, 0, stream>>>(
            H, Wt + (size_t)l * 2 * D * D + D * D, b2 + (size_t)l * D, N, 1,
            nullptr, out + (size_t)l * N * D, nextXB);
    }
}

// Round 3
// 669.280 us; speedup vs baseline: 1.5808x; 1.2221x over previous
//
#include <hip/hip_runtime.h>

#define D 128

typedef __attribute__((ext_vector_type(8))) short bf16x8;
typedef __attribute__((ext_vector_type(4))) float f32x4;

__device__ inline unsigned short f2b(float f) {
    union { float f; unsigned int u; } v; v.f = f;
    unsigned int u = v.u;
    u += 0x7fffu + ((u >> 16) & 1u);
    return (unsigned short)(u >> 16);
}
__device__ inline float bl(unsigned int u) { union { unsigned int u; float f; } c; c.u = u << 16; return c.f; }
__device__ inline float bh(unsigned int u) { union { unsigned int u; float f; } c; c.u = u & 0xffff0000u; return c.f; }

// ---------- edge dtype probe: int64 storage => odd int32 words are all zero ----------
__global__ void detect_dtype(const int* __restrict__ ei, int E, int* __restrict__ flag) {
    if (blockIdx.x == 0 && threadIdx.x == 0) {
        int z = 0;
        int nprobe = (E > 32) ? 32 : E;
        for (int i = 0; i < nprobe; i++) z |= ei[2 * i + 1];
        flag[0] = (z == 0) ? 1 : 0;
    }
}

// ---------- CSR build ----------
__global__ void count_deg(const int* __restrict__ ei, int E, int n,
                          const int* __restrict__ flag, int* __restrict__ deg) {
    int i = blockIdx.x * blockDim.x + threadIdx.x;
    if (i >= E) return;
    int m = flag[0];
    int d = m ? ei[2 * (E + i)] : ei[E + i];
    if (d >= 0 && d < n) atomicAdd(&deg[d], 1);
}

// two-level scan: per-block sums -> scan sums -> per-block scan+fill
__global__ void partial_sums(const int* __restrict__ deg, int* __restrict__ blksum, int n) {
    __shared__ int s[256];
    int i = blockIdx.x * 256 + threadIdx.x;
    s[threadIdx.x] = (i < n) ? deg[i] : 0;
    __syncthreads();
    for (int off = 128; off; off >>= 1) {
        if (threadIdx.x < off) s[threadIdx.x] += s[threadIdx.x + off];
        __syncthreads();
    }
    if (threadIdx.x == 0) blksum[blockIdx.x] = s[0];
}

__global__ void scan_blksum(int* __restrict__ blksum, int nb) {
    __shared__ int s[1024];
    __shared__ int base_s;
    int tid = threadIdx.x;
    if (tid == 0) base_s = 0;
    __syncthreads();
    for (int start = 0; start < nb; start += 1024) {
        int idx = start + tid;
        int v = (idx < nb) ? blksum[idx] : 0;
        s[tid] = v;
        __syncthreads();
        for (int off = 1; off < 1024; off <<= 1) {
            int t = (tid >= off) ? s[tid - off] : 0;
            __syncthreads();
            s[tid] += t;
            __syncthreads();
        }
        int total = s[1023];
        if (idx < nb) blksum[idx] = base_s + s[tid] - v;   // exclusive prefix
        __syncthreads();
        if (tid == 0) base_s += total;
        __syncthreads();
    }
}

__global__ void scan_fill(const int* __restrict__ deg, const int* __restrict__ blksum,
                          int* __restrict__ offsets, int n) {
    __shared__ int s[256];
    int tid = threadIdx.x;
    int i = blockIdx.x * 256 + tid;
    int v = (i < n) ? deg[i] : 0;
    s[tid] = v;
    __syncthreads();
    for (int off = 1; off < 256; off <<= 1) {
        int t = (tid >= off) ? s[tid - off] : 0;
        __syncthreads();
        s[tid] += t;
        __syncthreads();
    }
    if (i < n) offsets[i + 1] = blksum[blockIdx.x] + s[tid];  // global inclusive
    if (i == 0) offsets[0] = 0;
}

__global__ void fill_csr(const int* __restrict__ ei, int E, int n,
                         const int* __restrict__ flag, const int* __restrict__ offsets,
                         int* __restrict__ cursor, int* __restrict__ csr) {
    int i = blockIdx.x * blockDim.x + threadIdx.x;
    if (i >= E) return;
    int m = flag[0];
    int s = m ? ei[2 * i] : ei[i];
    int d = m ? ei[2 * (E + i)] : ei[E + i];
    if (d < 0 || d >= n) return;
    int pos = offsets[d] + atomicAdd(&cursor[d], 1);
    csr[pos] = s;
}

// ---------- weight transpose + bf16: Wt[l][which][c][k] = W[l][k][c] ----------
__global__ void conv_w(const float* __restrict__ W1, const float* __restrict__ W2,
                       unsigned short* __restrict__ Wt, int L) {
    int i = blockIdx.x * blockDim.x + threadIdx.x;
    int total = L * 2 * D * D;
    if (i >= total) return;
    int l = i / (2 * D * D);
    int rem = i - l * 2 * D * D;
    int which = rem / (D * D);
    int idx = rem - which * D * D;
    int c = idx >> 7, k = idx & 127;
    const float* W = which ? W2 : W1;
    Wt[i] = f2b(W[(size_t)l * D * D + k * D + c]);
}

// ---------- x (fp32) -> xb (bf16) ----------
__global__ void conv_x(const float* __restrict__ x, unsigned short* __restrict__ xb, int total4) {
    int i = blockIdx.x * blockDim.x + threadIdx.x;
    if (i >= total4) return;
    float4 v = ((const float4*)x)[i];
    uint2 o;
    o.x = (unsigned int)f2b(v.x) | ((unsigned int)f2b(v.y) << 16);
    o.y = (unsigned int)f2b(v.z) | ((unsigned int)f2b(v.w) << 16);
    ((uint2*)xb)[i] = o;
}

// ---------- aggregation, bf16 gather: A = bf16( xb[node] + sum xb[src] ) ----------
__global__ void agg_bf16(const unsigned short* __restrict__ xb, const int* __restrict__ csr,
                         const int* __restrict__ offs, unsigned short* __restrict__ A, int n) {
    int node = blockIdx.x * (blockDim.x >> 6) + (threadIdx.x >> 6);
    if (node >= n) return;
    int lane = threadIdx.x & 63;
    int half = lane >> 5, l32 = lane & 31;
    const uint2* xv = (const uint2*)xb;   // 32 uint2 per row

    float a0 = 0.f, a1 = 0.f, a2 = 0.f, a3 = 0.f;
    if (half == 0) {
        uint2 sv = xv[(size_t)node * 32 + l32];
        a0 += bl(sv.x); a1 += bh(sv.x); a2 += bl(sv.y); a3 += bh(sv.y);
    }
    int beg = offs[node], end = offs[node + 1];
    int i = beg + half;
    for (; i + 2 < end; i += 4) {
        int s0 = csr[i], s1 = csr[i + 2];
        uint2 v0 = xv[(size_t)s0 * 32 + l32];
        uint2 v1 = xv[(size_t)s1 * 32 + l32];
        a0 += bl(v0.x); a1 += bh(v0.x); a2 += bl(v0.y); a3 += bh(v0.y);
        a0 += bl(v1.x); a1 += bh(v1.x); a2 += bl(v1.y); a3 += bh(v1.y);
    }
    if (i < end) {
        int s0 = csr[i];
        uint2 v0 = xv[(size_t)s0 * 32 + l32];
        a0 += bl(v0.x); a1 += bh(v0.x); a2 += bl(v0.y); a3 += bh(v0.y);
    }
    a0 += __shfl_xor(a0, 32);
    a1 += __shfl_xor(a1, 32);
    a2 += __shfl_xor(a2, 32);
    a3 += __shfl_xor(a3, 32);
    if (half == 0) {
        uint2 o;
        o.x = (unsigned int)f2b(a0) | ((unsigned int)f2b(a1) << 16);
        o.y = (unsigned int)f2b(a2) | ((unsigned int)f2b(a3) << 16);
        ((uint2*)A)[(size_t)node * 32 + l32] = o;
    }
}

// ---------- aggregation, fp32 gather (fallback) ----------
__global__ void agg_f32(const float* __restrict__ x, const int* __restrict__ csr,
                        const int* __restrict__ offsets, unsigned short* __restrict__ A, int n) {
    int node = blockIdx.x * (blockDim.x >> 6) + (threadIdx.x >> 6);
    if (node >= n) return;
    int d2 = threadIdx.x & 63;
    const float2* xr = (const float2*)(x + (size_t)node * D);
    float2 acc = xr[d2];
    int beg = offsets[node], end = offsets[node + 1];
    for (int i = beg; i < end; i++) {
        int s = csr[i];
        float2 v = ((const float2*)(x + (size_t)s * D))[d2];
        acc.x += v.x; acc.y += v.y;
    }
    unsigned int pk = (unsigned int)f2b(acc.x) | ((unsigned int)f2b(acc.y) << 16);
    ((unsigned int*)(A + (size_t)node * D))[d2] = pk;
}

// ---------- GEMM: out = relu(Ain @ W + bias) ----------
__global__ __launch_bounds__(256) void gemm_bf16(
    const unsigned short* __restrict__ Ain,
    const unsigned short* __restrict__ Wt,
    const float* __restrict__ bias,
    int n, int storeF32,
    unsigned short* __restrict__ outB, float* __restrict__ outF,
    unsigned short* __restrict__ outXB) {

    int wave = threadIdx.x >> 6;
    int lane = threadIdx.x & 63;
    int l16 = lane & 15, g = lane >> 4;
    int rowbase = blockIdx.x * 128 + wave * 32;

    f32x4 acc[2][8];
    for (int rf = 0; rf < 2; rf++)
        for (int cf = 0; cf < 8; cf++)
            acc[rf][cf] = (f32x4){0.f, 0.f, 0.f, 0.f};

    for (int ks = 0; ks < 4; ks++) {
        int k0 = ks * 32 + g * 8;
        bf16x8 a[2];
        #pragma unroll
        for (int rf = 0; rf < 2; rf++) {
            int row = rowbase + rf * 16 + l16;
            if (row >= n) row = n - 1;
            a[rf] = *((const bf16x8*)(Ain + (size_t)row * D + k0));
        }
        #pragma unroll
        for (int cf = 0; cf < 8; cf++) {
            int col = cf * 16 + l16;
            bf16x8 b = *((const bf16x8*)(Wt + col * D + k0));
            acc[0][cf] = __builtin_amdgcn_mfma_f32_16x16x32_bf16(a[0], b, acc[0][cf], 0, 0, 0);
            acc[1][cf] = __builtin_amdgcn_mfma_f32_16x16x32_bf16(a[1], b, acc[1][cf], 0, 0, 0);
        }
    }

    #pragma unroll
    for (int cf = 0; cf < 8; cf++) {
        int col = cf * 16 + l16;
        float bv = bias[col];
        #pragma unroll
        for (int rf = 0; rf < 2; rf++) {
            #pragma unroll
            for (int r = 0; r < 4; r++) {
                int row = rowbase + rf * 16 + g * 4 + r;
                if (row < n) {
                    float v = acc[rf][cf][r] + bv;
                    v = (v < 0.f) ? 0.f : v;
                    if (storeF32) {
                        outF[(size_t)row * D + col] = v;
                        if (outXB) outXB[(size_t)row * D + col] = f2b(v);
                    } else {
                        outB[(size_t)row * D + col] = f2b(v);
                    }
                }
            }
        }
    }
}

extern "C" void kernel_launch(void* const* d_in, const int* in_sizes, int n_in,
                              void* d_out, int out_size, void* d_ws, size_t ws_size,
                              hipStream_t stream) {
    const float* x  = (const float*)d_in[0];
    const int*   ei = (const int*)d_in[1];
    const float* W1 = (const float*)d_in[2];
    const float* b1 = (const float*)d_in[3];
    const float* W2 = (const float*)d_in[4];
    const float* b2 = (const float*)d_in[5];
    float* out = (float*)d_out;

    int N = in_sizes[0] / D;
    int E = in_sizes[1] / 2;
    int L = in_sizes[3] / D;
    int NB = (N + 255) / 256;

    auto alignup = [](size_t v) { return (v + 255) & ~(size_t)255; };
    size_t sz_flag = 256;
    size_t sz_deg  = alignup((size_t)N * 4);
    size_t sz_offs = alignup((size_t)(N + 1) * 4);
    size_t sz_cur  = alignup((size_t)N * 4);
    size_t sz_blk  = alignup((size_t)NB * 4);
    size_t sz_csr  = alignup((size_t)E * 4);
    size_t sz_wt   = alignup((size_t)L * 2 * D * D * 2);
    size_t sz_mat  = alignup((size_t)N * D * 2);
    size_t base = sz_flag + sz_deg + sz_offs + sz_cur + sz_blk + sz_csr + sz_wt;
    bool useBf16 = (base + 3 * sz_mat) <= ws_size;

    char* p = (char*)d_ws;
    int* flag    = (int*)p;            p += sz_flag;
    int* deg     = (int*)p;            p += sz_deg;
    int* offs    = (int*)p;            p += sz_offs;
    int* cursor  = (int*)p;            p += sz_cur;
    int* blksum  = (int*)p;            p += sz_blk;
    int* csr     = (int*)p;            p += sz_csr;
    unsigned short* Wt = (unsigned short*)p; p += sz_wt;
    unsigned short* A  = (unsigned short*)p; p += sz_mat;
    unsigned short* H  = (unsigned short*)p; p += sz_mat;
    unsigned short* XB = (unsigned short*)p;

    hipMemsetAsync(deg, 0, (size_t)N * 4, stream);
    hipMemsetAsync(cursor, 0, (size_t)N * 4, stream);

    detect_dtype<<<1, 64, 0, stream>>>(ei, E, flag);
    count_deg<<<(E + 255) / 256, 256, 0, stream>>>(ei, E, N, flag, deg);
    partial_sums<<<NB, 256, 0, stream>>>(deg, blksum, N);
    scan_blksum<<<1, 1024, 0, stream>>>(blksum, NB);
    scan_fill<<<NB, 256, 0, stream>>>(deg, blksum, offs, N);
    fill_csr<<<(E + 255) / 256, 256, 0, stream>>>(ei, E, N, flag, offs, cursor, csr);
    conv_w<<<(L * 2 * D * D + 255) / 256, 256, 0, stream>>>(W1, W2, Wt, L);
    if (useBf16)
        conv_x<<<(N * D / 4 + 255) / 256, 256, 0, stream>>>(x, XB, N * D / 4);

    for (int l = 0; l < L; l++) {
        if (useBf16) {
            agg_bf16<<<(N + 3) / 4, 256, 0, stream>>>(XB, csr, offs, A, N);
        } else {
            const float* xin = (l == 0) ? x : out + (size_t)(l - 1) * N * D;
            agg_f32<<<(N + 3) / 4, 256, 0, stream>>>(xin, csr, offs, A, N);
        }
        gemm_bf16<<<(N + 127) / 128, 256, 0, stream>>>(
            A, Wt + (size_t)l * 2 * D * D, b1 + (size_t)l * D, N, 0, H, nullptr, nullptr);
        unsigned short* nextXB = (useBf16 && l + 1 < L) ? XB : nullptr;
        gemm_bf16<<<(N + 127) / 128, 256, 0, stream>>>(
            H, Wt + (size_t)l * 2 * D * D + D * D, b2 + (size_t)l * D, N, 1,
            nullptr, out + (size_t)l * N * D, nextXB);
    }
}

// Round 4
// 578.377 us; speedup vs baseline: 1.8292x; 1.1572x over previous
//
#include <hip/hip_runtime.h>

#define D 128

typedef __attribute__((ext_vector_type(8))) short bf16x8;
typedef __attribute__((ext_vector_type(4))) float f32x4;

__device__ inline unsigned short f2b(float f) {
    union { float f; unsigned int u; } v; v.f = f;
    unsigned int u = v.u;
    u += 0x7fffu + ((u >> 16) & 1u);
    return (unsigned short)(u >> 16);
}
__device__ inline float bl(unsigned int u) { union { unsigned int u; float f; } c; c.u = u << 16; return c.f; }
__device__ inline float bh(unsigned int u) { union { unsigned int u; float f; } c; c.u = u & 0xffff0000u; return c.f; }

// ---------- edge dtype probe: int64 storage => odd int32 words are all zero ----------
__global__ void detect_dtype(const int* __restrict__ ei, int E, int* __restrict__ flag) {
    if (blockIdx.x == 0 && threadIdx.x == 0) {
        int z = 0;
        int nprobe = (E > 32) ? 32 : E;
        for (int i = 0; i < nprobe; i++) z |= ei[2 * i + 1];
        flag[0] = (z == 0) ? 1 : 0;
    }
}

// ---------- XCD-partitioned CSR build ----------
// grp = blockIdx & 7 lands on one XCD under round-robin dispatch; each group
// owns dst range [r0,r1) so cursor atomics + csr/deg lines stay XCD-local.
__global__ void count_deg_part(const int* __restrict__ ei, int E, int n,
                               const int* __restrict__ flag, int* __restrict__ deg) {
    int grp = blockIdx.x & 7;
    int per = n >> 3;
    int r0 = grp * per;
    int r1 = (grp == 7) ? n : r0 + per;
    int m = flag[0];
    int tpg = (gridDim.x >> 3) * blockDim.x;
    int idx = (blockIdx.x >> 3) * blockDim.x + threadIdx.x;
    for (int i = idx; i < E; i += tpg) {
        int d = m ? ei[2 * (E + i)] : ei[E + i];
        if (d >= r0 && d < r1) atomicAdd(&deg[d], 1);
    }
}

__global__ void fill_csr_part(const int* __restrict__ ei, int E, int n,
                              const int* __restrict__ flag, const int* __restrict__ offsets,
                              int* __restrict__ cursor, int* __restrict__ csr) {
    int grp = blockIdx.x & 7;
    int per = n >> 3;
    int r0 = grp * per;
    int r1 = (grp == 7) ? n : r0 + per;
    int m = flag[0];
    int tpg = (gridDim.x >> 3) * blockDim.x;
    int idx = (blockIdx.x >> 3) * blockDim.x + threadIdx.x;
    for (int i = idx; i < E; i += tpg) {
        int d = m ? ei[2 * (E + i)] : ei[E + i];
        if (d >= r0 && d < r1) {
            int s = m ? ei[2 * i] : ei[i];
            int pos = offsets[d] + atomicAdd(&cursor[d], 1);
            csr[pos] = s;
        }
    }
}

// ---------- two-level scan ----------
__global__ void partial_sums(const int* __restrict__ deg, int* __restrict__ blksum, int n) {
    __shared__ int s[256];
    int i = blockIdx.x * 256 + threadIdx.x;
    s[threadIdx.x] = (i < n) ? deg[i] : 0;
    __syncthreads();
    for (int off = 128; off; off >>= 1) {
        if (threadIdx.x < off) s[threadIdx.x] += s[threadIdx.x + off];
        __syncthreads();
    }
    if (threadIdx.x == 0) blksum[blockIdx.x] = s[0];
}

__global__ void scan_blksum(int* __restrict__ blksum, int nb) {
    __shared__ int s[1024];
    __shared__ int base_s;
    int tid = threadIdx.x;
    if (tid == 0) base_s = 0;
    __syncthreads();
    for (int start = 0; start < nb; start += 1024) {
        int idx = start + tid;
        int v = (idx < nb) ? blksum[idx] : 0;
        s[tid] = v;
        __syncthreads();
        for (int off = 1; off < 1024; off <<= 1) {
            int t = (tid >= off) ? s[tid - off] : 0;
            __syncthreads();
            s[tid] += t;
            __syncthreads();
        }
        int total = s[1023];
        if (idx < nb) blksum[idx] = base_s + s[tid] - v;
        __syncthreads();
        if (tid == 0) base_s += total;
        __syncthreads();
    }
}

__global__ void scan_fill(const int* __restrict__ deg, const int* __restrict__ blksum,
                          int* __restrict__ offsets, int n) {
    __shared__ int s[256];
    int tid = threadIdx.x;
    int i = blockIdx.x * 256 + tid;
    int v = (i < n) ? deg[i] : 0;
    s[tid] = v;
    __syncthreads();
    for (int off = 1; off < 256; off <<= 1) {
        int t = (tid >= off) ? s[tid - off] : 0;
        __syncthreads();
        s[tid] += t;
        __syncthreads();
    }
    if (i < n) offsets[i + 1] = blksum[blockIdx.x] + s[tid];
    if (i == 0) offsets[0] = 0;
}

// ---------- weight transpose + bf16: Wt[l][which][c][k] = W[l][k][c] ----------
__global__ void conv_w(const float* __restrict__ W1, const float* __restrict__ W2,
                       unsigned short* __restrict__ Wt, int L) {
    int i = blockIdx.x * blockDim.x + threadIdx.x;
    int total = L * 2 * D * D;
    if (i >= total) return;
    int l = i / (2 * D * D);
    int rem = i - l * 2 * D * D;
    int which = rem / (D * D);
    int idx = rem - which * D * D;
    int c = idx >> 7, k = idx & 127;
    const float* W = which ? W2 : W1;
    Wt[i] = f2b(W[(size_t)l * D * D + k * D + c]);
}

// ---------- x (fp32) -> xb (bf16) ----------
__global__ void conv_x(const float* __restrict__ x, unsigned short* __restrict__ xb, int total4) {
    int i = blockIdx.x * blockDim.x + threadIdx.x;
    if (i >= total4) return;
    float4 v = ((const float4*)x)[i];
    uint2 o;
    o.x = (unsigned int)f2b(v.x) | ((unsigned int)f2b(v.y) << 16);
    o.y = (unsigned int)f2b(v.z) | ((unsigned int)f2b(v.w) << 16);
    ((uint2*)xb)[i] = o;
}

// ---------- aggregation, bf16 gather, 4 rows in flight per half-wave ----------
__global__ void agg_bf16(const unsigned short* __restrict__ xb, const int* __restrict__ csr,
                         const int* __restrict__ offs, unsigned short* __restrict__ A, int n) {
    int node = blockIdx.x * (blockDim.x >> 6) + (threadIdx.x >> 6);
    if (node >= n) return;
    int lane = threadIdx.x & 63;
    int half = lane >> 5, l32 = lane & 31;
    const uint2* xv = (const uint2*)xb;

    float a0 = 0.f, a1 = 0.f, a2 = 0.f, a3 = 0.f;
    if (half == 0) {
        uint2 sv = xv[(size_t)node * 32 + l32];
        a0 += bl(sv.x); a1 += bh(sv.x); a2 += bl(sv.y); a3 += bh(sv.y);
    }
    int beg = offs[node], end = offs[node + 1];
    int i = beg + half;
    for (; i + 6 < end; i += 8) {
        int s0 = csr[i], s1 = csr[i + 2], s2 = csr[i + 4], s3 = csr[i + 6];
        uint2 v0 = xv[(size_t)s0 * 32 + l32];
        uint2 v1 = xv[(size_t)s1 * 32 + l32];
        uint2 v2 = xv[(size_t)s2 * 32 + l32];
        uint2 v3 = xv[(size_t)s3 * 32 + l32];
        a0 += bl(v0.x); a1 += bh(v0.x); a2 += bl(v0.y); a3 += bh(v0.y);
        a0 += bl(v1.x); a1 += bh(v1.x); a2 += bl(v1.y); a3 += bh(v1.y);
        a0 += bl(v2.x); a1 += bh(v2.x); a2 += bl(v2.y); a3 += bh(v2.y);
        a0 += bl(v3.x); a1 += bh(v3.x); a2 += bl(v3.y); a3 += bh(v3.y);
    }
    for (; i < end; i += 2) {
        int s0 = csr[i];
        uint2 v0 = xv[(size_t)s0 * 32 + l32];
        a0 += bl(v0.x); a1 += bh(v0.x); a2 += bl(v0.y); a3 += bh(v0.y);
    }
    a0 += __shfl_xor(a0, 32);
    a1 += __shfl_xor(a1, 32);
    a2 += __shfl_xor(a2, 32);
    a3 += __shfl_xor(a3, 32);
    if (half == 0) {
        uint2 o;
        o.x = (unsigned int)f2b(a0) | ((unsigned int)f2b(a1) << 16);
        o.y = (unsigned int)f2b(a2) | ((unsigned int)f2b(a3) << 16);
        ((uint2*)A)[(size_t)node * 32 + l32] = o;
    }
}

// ---------- aggregation, fp32 gather (fallback) ----------
__global__ void agg_f32(const float* __restrict__ x, const int* __restrict__ csr,
                        const int* __restrict__ offsets, unsigned short* __restrict__ A, int n) {
    int node = blockIdx.x * (blockDim.x >> 6) + (threadIdx.x >> 6);
    if (node >= n) return;
    int d2 = threadIdx.x & 63;
    const float2* xr = (const float2*)(x + (size_t)node * D);
    float2 acc = xr[d2];
    int beg = offsets[node], end = offsets[node + 1];
    for (int i = beg; i < end; i++) {
        int s = csr[i];
        float2 v = ((const float2*)(x + (size_t)s * D))[d2];
        acc.x += v.x; acc.y += v.y;
    }
    unsigned int pk = (unsigned int)f2b(acc.x) | ((unsigned int)f2b(acc.y) << 16);
    ((unsigned int*)(A + (size_t)node * D))[d2] = pk;
}

// ---------- fused MLP: out = relu( relu(A@W1+b1) @ W2 + b2 ); H lives in LDS ----------
__global__ __launch_bounds__(256) void mlp_fused(
    const unsigned short* __restrict__ Ain,
    const unsigned short* __restrict__ Wt1,   // [col][k] bf16
    const unsigned short* __restrict__ Wt2,   // [col][k] bf16
    const float* __restrict__ b1, const float* __restrict__ b2,
    int n, float* __restrict__ outF, unsigned short* __restrict__ outXB) {

    __shared__ unsigned char Hs[128 * 128 * 2];   // 32 KB, XOR-swizzled

    int wave = threadIdx.x >> 6;
    int lane = threadIdx.x & 63;
    int l16 = lane & 15, g = lane >> 4;
    int rowbase = blockIdx.x * 128 + wave * 32;

    // ---- GEMM1: acc = A @ W1 ----
    f32x4 acc[2][8];
    #pragma unroll
    for (int rf = 0; rf < 2; rf++)
        #pragma unroll
        for (int cf = 0; cf < 8; cf++)
            acc[rf][cf] = (f32x4){0.f, 0.f, 0.f, 0.f};

    #pragma unroll
    for (int ks = 0; ks < 4; ks++) {
        int k0 = ks * 32 + g * 8;
        bf16x8 a[2];
        #pragma unroll
        for (int rf = 0; rf < 2; rf++) {
            int row = rowbase + rf * 16 + l16;
            if (row >= n) row = n - 1;
            a[rf] = *((const bf16x8*)(Ain + (size_t)row * D + k0));
        }
        #pragma unroll
        for (int cf = 0; cf < 8; cf++) {
            int col = cf * 16 + l16;
            bf16x8 b = *((const bf16x8*)(Wt1 + col * D + k0));
            acc[0][cf] = __builtin_amdgcn_mfma_f32_16x16x32_bf16(a[0], b, acc[0][cf], 0, 0, 0);
            acc[1][cf] = __builtin_amdgcn_mfma_f32_16x16x32_bf16(a[1], b, acc[1][cf], 0, 0, 0);
        }
    }

    // ---- epilogue1: relu(acc + b1) -> bf16 -> LDS (swizzled [row][col]) ----
    #pragma unroll
    for (int cf = 0; cf < 8; cf++) {
        int col = cf * 16 + l16;
        float bv = b1[col];
        #pragma unroll
        for (int rf = 0; rf < 2; rf++) {
            #pragma unroll
            for (int r = 0; r < 4; r++) {
                int rl = wave * 32 + rf * 16 + g * 4 + r;   // row within 128-tile
                float v = acc[rf][cf][r] + bv;
                v = (v < 0.f) ? 0.f : v;
                int byte = (rl * 256 + col * 2) ^ ((rl & 7) << 4);
                *(unsigned short*)(Hs + byte) = f2b(v);
            }
        }
    }
    __syncthreads();

    // ---- GEMM2: acc2 = H @ W2 ----
    f32x4 acc2[2][8];
    #pragma unroll
    for (int rf = 0; rf < 2; rf++)
        #pragma unroll
        for (int cf = 0; cf < 8; cf++)
            acc2[rf][cf] = (f32x4){0.f, 0.f, 0.f, 0.f};

    #pragma unroll
    for (int ks = 0; ks < 4; ks++) {
        int k0 = ks * 32 + g * 8;
        bf16x8 a[2];
        #pragma unroll
        for (int rf = 0; rf < 2; rf++) {
            int rl = wave * 32 + rf * 16 + l16;
            int byte = (rl * 256 + k0 * 2) ^ ((rl & 7) << 4);
            a[rf] = *(const bf16x8*)(Hs + byte);
        }
        #pragma unroll
        for (int cf = 0; cf < 8; cf++) {
            int col = cf * 16 + l16;
            bf16x8 b = *((const bf16x8*)(Wt2 + col * D + k0));
            acc2[0][cf] = __builtin_amdgcn_mfma_f32_16x16x32_bf16(a[0], b, acc2[0][cf], 0, 0, 0);
            acc2[1][cf] = __builtin_amdgcn_mfma_f32_16x16x32_bf16(a[1], b, acc2[1][cf], 0, 0, 0);
        }
    }

    // ---- epilogue2: relu(acc2 + b2) -> fp32 out (+ bf16 XB) ----
    #pragma unroll
    for (int cf = 0; cf < 8; cf++) {
        int col = cf * 16 + l16;
        float bv = b2[col];
        #pragma unroll
        for (int rf = 0; rf < 2; rf++) {
            #pragma unroll
            for (int r = 0; r < 4; r++) {
                int row = rowbase + rf * 16 + g * 4 + r;
                if (row < n) {
                    float v = acc2[rf][cf][r] + bv;
                    v = (v < 0.f) ? 0.f : v;
                    outF[(size_t)row * D + col] = v;
                    if (outXB) outXB[(size_t)row * D + col] = f2b(v);
                }
            }
        }
    }
}

extern "C" void kernel_launch(void* const* d_in, const int* in_sizes, int n_in,
                              void* d_out, int out_size, void* d_ws, size_t ws_size,
                              hipStream_t stream) {
    const float* x  = (const float*)d_in[0];
    const int*   ei = (const int*)d_in[1];
    const float* W1 = (const float*)d_in[2];
    const float* b1 = (const float*)d_in[3];
    const float* W2 = (const float*)d_in[4];
    const float* b2 = (const float*)d_in[5];
    float* out = (float*)d_out;

    int N = in_sizes[0] / D;
    int E = in_sizes[1] / 2;
    int L = in_sizes[3] / D;
    int NB = (N + 255) / 256;

    auto alignup = [](size_t v) { return (v + 255) & ~(size_t)255; };
    size_t sz_flag = 256;
    size_t sz_deg  = alignup((size_t)N * 4);
    size_t sz_offs = alignup((size_t)(N + 1) * 4);
    size_t sz_cur  = alignup((size_t)N * 4);
    size_t sz_blk  = alignup((size_t)NB * 4);
    size_t sz_csr  = alignup((size_t)E * 4);
    size_t sz_wt   = alignup((size_t)L * 2 * D * D * 2);
    size_t sz_mat  = alignup((size_t)N * D * 2);
    size_t base = sz_flag + sz_deg + sz_offs + sz_cur + sz_blk + sz_csr + sz_wt;
    bool useBf16 = (base + 2 * sz_mat) <= ws_size;

    char* p = (char*)d_ws;
    int* flag    = (int*)p;            p += sz_flag;
    int* deg     = (int*)p;            p += sz_deg;
    int* offs    = (int*)p;            p += sz_offs;
    int* cursor  = (int*)p;            p += sz_cur;
    int* blksum  = (int*)p;            p += sz_blk;
    int* csr     = (int*)p;            p += sz_csr;
    unsigned short* Wt = (unsigned short*)p; p += sz_wt;
    unsigned short* A  = (unsigned short*)p; p += sz_mat;
    unsigned short* XB = (unsigned short*)p;

    hipMemsetAsync(deg, 0, (size_t)N * 4, stream);
    hipMemsetAsync(cursor, 0, (size_t)N * 4, stream);

    detect_dtype<<<1, 64, 0, stream>>>(ei, E, flag);
    count_deg_part<<<2048, 256, 0, stream>>>(ei, E, N, flag, deg);
    partial_sums<<<NB, 256, 0, stream>>>(deg, blksum, N);
    scan_blksum<<<1, 1024, 0, stream>>>(blksum, NB);
    scan_fill<<<NB, 256, 0, stream>>>(deg, blksum, offs, N);
    fill_csr_part<<<2048, 256, 0, stream>>>(ei, E, N, flag, offs, cursor, csr);
    conv_w<<<(L * 2 * D * D + 255) / 256, 256, 0, stream>>>(W1, W2, Wt, L);
    if (useBf16)
        conv_x<<<(N * D / 4 + 255) / 256, 256, 0, stream>>>(x, XB, N * D / 4);

    for (int l = 0; l < L; l++) {
        if (useBf16) {
            agg_bf16<<<(N + 3) / 4, 256, 0, stream>>>(XB, csr, offs, A, N);
        } else {
            const float* xin = (l == 0) ? x : out + (size_t)(l - 1) * N * D;
            agg_f32<<<(N + 3) / 4, 256, 0, stream>>>(xin, csr, offs, A, N);
        }
        unsigned short* nextXB = (useBf16 && l + 1 < L) ? XB : nullptr;
        mlp_fused<<<(N + 127) / 128, 256, 0, stream>>>(
            A, Wt + (size_t)l * 2 * D * D, Wt + (size_t)l * 2 * D * D + D * D,
            b1 + (size_t)l * D, b2 + (size_t)l * D, N,
            out + (size_t)l * N * D, nextXB);
    }
}